// Round 4
// baseline (1384.553 us; speedup 1.0000x reference)
//
#include <hip/hip_runtime.h>
#include <math.h>

// VQ quantizer: z [65536, 256] fp32, codebook [1024, 256] fp32.
// Outputs flat: z_q [16777216] | loss [1] | indices [65536] (as float values).
//
// Numerics contract (validated in R1, absmax 0.0 — keep bit-identical):
//   A_t = sum(z_t^2)  -- numpy pairwise order (8-acc chains, 128-blocks, fixed tree)
//   B_n = sum(e_n^2)  -- same
//   d   = fl( fl(A+B) - 2*M ),  M = fp32 fma-accumulated dot
//   argmin: global first-min == lexicographic min of key (d_bits<<32 | idx)
//   z_q_out = fl( z + fl(e - z) ),  loss = fl(mf + fl(10*mf)), mf=(float)(Σdx²/2^24)

#define NTOK     65536
#define DDIM     256
#define NCODE    1024
#define LOSS_OFF 16777216
#define IDX_OFF  16777217

// ws layout: [0] double loss_acc | [64] float wsB[1024] | [8192] u64 keys[65536]

// ---------------- kernel 0: B_n (numpy-pairwise), zero loss, init argmin keys.
__global__ void vq_prep(const float* __restrict__ cb, float* __restrict__ wsB,
                        double* __restrict__ loss_acc,
                        unsigned long long* __restrict__ keys)
{
#pragma clang fp contract(off)
    int gid = blockIdx.x * blockDim.x + threadIdx.x;
    if (gid == 0) *loss_acc = 0.0;
    unsigned long long* kp = keys + (size_t)gid * 4;
    kp[0] = kp[1] = kp[2] = kp[3] = 0xFFFFFFFFFFFFFFFFull;
    if (gid >= NCODE) return;
    const float* a = cb + gid * DDIM;
    float half[2];
    for (int h = 0; h < 2; ++h) {
        const float* b = a + h * 128;
        float r[8];
#pragma unroll
        for (int j = 0; j < 8; ++j) { float v = b[j]; r[j] = v * v; }
        for (int i = 8; i < 128; i += 8) {
#pragma unroll
            for (int j = 0; j < 8; ++j) { float v = b[i + j]; float s = v * v; r[j] = r[j] + s; }
        }
        half[h] = ((r[0] + r[1]) + (r[2] + r[3])) + ((r[4] + r[5]) + (r[6] + r[7]));
    }
    wsB[gid] = half[0] + half[1];
}

// ---------------- kernel 1: distance GEMM + per-tile argmin -> atomicMin keys.
// Grid 4096: block b -> xcd = b&7, s = b>>3, token-tile tt = xcd*64 + (s>>3),
// code-tile ct = s&7. The 8 sibling blocks of a token-tile have ids spaced 8
// apart (same XCD by id%8 round-robin) so the z-tile stays hot in that L2.
__global__ __launch_bounds__(256, 4) void vq_main(const float* __restrict__ z,
                                                  const float* __restrict__ cb,
                                                  const float* __restrict__ wsB,
                                                  unsigned long long* __restrict__ keys)
{
    __shared__ float zs[32][128];   // [k][token phys]  16 KB (XOR-swizzled)
    __shared__ float es[32][128];   // [k][code phys]   16 KB (XOR-swizzled)
    __shared__ float Bl[128];
    __shared__ float sA[128][2];

    const int tid = threadIdx.x;
    const int tx = tid & 15, ty = tid >> 4;
    const int b = blockIdx.x;
    const int xcd = b & 7, sl = b >> 3;
    const int tt = xcd * 64 + (sl >> 3);
    const int ct = sl & 7;
    const int t0 = tt * 128;
    const int n0 = ct * 128;

    if (tid < 128) Bl[tid] = wsB[n0 + tid];

    // numpy-pairwise chains for A: thread -> (token = tid>>1, half = tid&1)
    float r[8];
#pragma unroll
    for (int j = 0; j < 8; ++j) r[j] = 0.0f;
    const int atok = tid >> 1, ah = tid & 1;

    float acc[8][8];
#pragma unroll
    for (int i = 0; i < 8; ++i)
#pragma unroll
        for (int j = 0; j < 8; ++j) acc[i][j] = 0.0f;

    float4 zr[4], er[4];

#define STAGE_LOAD(kc_)                                                           \
    {                                                                             \
        const float* zb_ = z  + (size_t)t0 * DDIM + (kc_) * 32;                   \
        const float* eb_ = cb + (size_t)n0 * DDIM + (kc_) * 32;                   \
        _Pragma("unroll")                                                         \
        for (int s_ = 0; s_ < 4; ++s_) {                                          \
            int g_ = tid + 256 * s_; int row_ = g_ >> 3; int c4_ = g_ & 7;        \
            zr[s_] = *(const float4*)(zb_ + row_ * DDIM + c4_ * 4);               \
            er[s_] = *(const float4*)(eb_ + row_ * DDIM + c4_ * 4);               \
        }                                                                         \
    }

    STAGE_LOAD(0);

    for (int kc = 0; kc < 8; ++kc) {
        __syncthreads();
        // transpose staging writes, XOR-swizzled: phys col p = row ^ ((k>>2)&3)<<3
        // (k = c4*4+j so (k>>2)&3 = c4&3, constant per lane across j)
#pragma unroll
        for (int s_ = 0; s_ < 4; ++s_) {
            int g = tid + 256 * s_; int row = g >> 3; int c4 = g & 7;
            int p = row ^ ((c4 & 3) << 3);
            zs[c4 * 4 + 0][p] = zr[s_].x; zs[c4 * 4 + 1][p] = zr[s_].y;
            zs[c4 * 4 + 2][p] = zr[s_].z; zs[c4 * 4 + 3][p] = zr[s_].w;
            es[c4 * 4 + 0][p] = er[s_].x; es[c4 * 4 + 1][p] = er[s_].y;
            es[c4 * 4 + 2][p] = er[s_].z; es[c4 * 4 + 3][p] = er[s_].w;
        }
        __syncthreads();
        if (kc < 7) STAGE_LOAD(kc + 1);

        // fold numpy-pairwise ||z||^2 chains (half ah) from staged LDS
        if ((kc >> 2) == ah) {
#pragma clang fp contract(off)
#pragma unroll
            for (int g = 0; g < 4; ++g)
#pragma unroll
                for (int j = 0; j < 8; ++j) {
                    int k = g * 8 + j;
                    float v = zs[k][atok ^ (((k >> 2) & 3) << 3)];
                    float s2 = v * v;
                    r[j] = r[j] + s2;
                }
        }

        // 32 k-steps: 4 x ds_read_b128 + 64 fp32 FMA per thread per step
#pragma unroll
        for (int k = 0; k < 32; ++k) {
            int cx = ((k >> 2) & 3) << 1;   // float4-granular XOR
            float4 a0 = *(const float4*)&zs[k][4 * (ty ^ cx)];
            float4 a1 = *(const float4*)&zs[k][64 + 4 * (ty ^ cx)];
            float4 b0 = *(const float4*)&es[k][4 * (tx ^ cx)];
            float4 b1 = *(const float4*)&es[k][64 + 4 * (tx ^ cx)];
            float za[8] = {a0.x, a0.y, a0.z, a0.w, a1.x, a1.y, a1.z, a1.w};
            float eb[8] = {b0.x, b0.y, b0.z, b0.w, b1.x, b1.y, b1.z, b1.w};
#pragma unroll
            for (int i = 0; i < 8; ++i)
#pragma unroll
                for (int j = 0; j < 8; ++j)
                    acc[i][j] = __builtin_fmaf(za[i], eb[j], acc[i][j]);
        }
    }

    // A: numpy combine tree per half, exchange halves via LDS
    {
        float sH = ((r[0] + r[1]) + (r[2] + r[3])) + ((r[4] + r[5]) + (r[6] + r[7]));
        sA[atok][ah] = sH;
    }
    __syncthreads();
    float Aval[8];
#pragma unroll
    for (int i = 0; i < 8; ++i) {
        int tl = (i < 4) ? (4 * ty + i) : (64 + 4 * ty + (i - 4));
        Aval[i] = sA[tl][0] + sA[tl][1];
    }

    // d = fl(fl(A+B) - 2*M); within-tile first-min (ascending n, strict <)
    float best[8];
    int   bidx[8];
#pragma unroll
    for (int i = 0; i < 8; ++i) { best[i] = __builtin_inff(); bidx[i] = 0x7fffffff; }
#pragma unroll
    for (int i = 0; i < 8; ++i)
#pragma unroll
        for (int j = 0; j < 8; ++j) {
            int cl = (j < 4) ? (4 * tx + j) : (64 + 4 * tx + (j - 4));
            float t1 = Aval[i] + Bl[cl];
            float dist = t1 - 2.0f * acc[i][j];
            if (dist < best[i]) { best[i] = dist; bidx[i] = n0 + cl; }
        }

    // lexicographic (d, idx) min over the 16 tx-threads per token
#pragma unroll
    for (int i = 0; i < 8; ++i) {
        float d = best[i]; int w = bidx[i];
        for (int off = 8; off; off >>= 1) {
            float od = __shfl_xor(d, off);
            int   ow = __shfl_xor(w, off);
            if (od < d || (od == d && ow < w)) { d = od; w = ow; }
        }
        best[i] = d; bidx[i] = w;
    }

    // merge across code-tiles: key = d_bits<<32 | idx (d>0 so bits are monotone)
    if (tx == 0) {
#pragma unroll
        for (int i = 0; i < 8; ++i) {
            int tl = (i < 4) ? (4 * ty + i) : (64 + 4 * ty + (i - 4));
            unsigned long long key =
                ((unsigned long long)__float_as_uint(best[i]) << 32) |
                (unsigned int)bidx[i];
            atomicMin(&keys[t0 + tl], key);
        }
    }
#undef STAGE_LOAD
}

// ---------------- kernel 2: gather z_q, indices, fp64 loss partials.
// Grid 1024 x 256: block owns 64 tokens; 16 tx-threads cooperate per token row.
__global__ __launch_bounds__(256) void vq_gather(const float* __restrict__ z,
                                                 const float* __restrict__ cb,
                                                 const unsigned long long* __restrict__ keys,
                                                 double* __restrict__ loss_acc,
                                                 float* __restrict__ out)
{
    __shared__ double lred[4];
    const int tid = threadIdx.x;
    const int tx = tid & 15, ty = tid >> 4;
    const int t0 = blockIdx.x * 64;

    double ld = 0.0;
#pragma unroll
    for (int i = 0; i < 4; ++i) {
        int t = t0 + ty * 4 + i;
        unsigned long long key = keys[t];
        int w = (int)(unsigned int)(key & 0xFFFFFFFFull);
        const float4* crow = (const float4*)(cb + (size_t)w * DDIM);
        const float4* zrow = (const float4*)(z + (size_t)t * DDIM);
        float4* orow = (float4*)(out + (size_t)t * DDIM);
#pragma unroll
        for (int q = 0; q < 4; ++q) {
            int c4 = tx * 4 + q;
            float4 e4 = crow[c4];
            float4 z4 = zrow[c4];
            float4 o;
            float dx;
            dx = e4.x - z4.x; o.x = z4.x + dx; ld += (double)(dx * dx);
            dx = e4.y - z4.y; o.y = z4.y + dx; ld += (double)(dx * dx);
            dx = e4.z - z4.z; o.z = z4.z + dx; ld += (double)(dx * dx);
            dx = e4.w - z4.w; o.w = z4.w + dx; ld += (double)(dx * dx);
            orow[c4] = o;
        }
        if (tx == 0) out[IDX_OFF + t] = (float)w;
    }

    for (int off = 32; off; off >>= 1) ld += __shfl_down(ld, off);
    int lane = tid & 63, wv = tid >> 6;
    if (lane == 0) lred[wv] = ld;
    __syncthreads();
    if (tid == 0) {
        double s = (lred[0] + lred[1]) + (lred[2] + lred[3]);
        atomicAdd(loss_acc, s);
    }
}

// ---------------- kernel 3: finalize loss = fl(mf + fl(10*mf))
__global__ void vq_finish(const double* __restrict__ loss_acc, float* __restrict__ out)
{
#pragma clang fp contract(off)
    double m = *loss_acc / 16777216.0;
    float mf = (float)m;
    float second = 10.0f * mf;
    out[LOSS_OFF] = mf + second;
}

extern "C" void kernel_launch(void* const* d_in, const int* in_sizes, int n_in,
                              void* d_out, int out_size, void* d_ws, size_t ws_size,
                              hipStream_t stream)
{
    (void)in_sizes; (void)n_in; (void)out_size; (void)ws_size;
    const float* z  = (const float*)d_in[0];
    const float* cb = (const float*)d_in[1];
    float* out = (float*)d_out;
    double* loss_acc = (double*)d_ws;                                  // 8 B
    float* wsB = (float*)((char*)d_ws + 64);                           // 4 KB
    unsigned long long* keys = (unsigned long long*)((char*)d_ws + 8192); // 512 KB

    vq_prep<<<dim3(64), dim3(256), 0, stream>>>(cb, wsB, loss_acc, keys);
    vq_main<<<dim3(4096), dim3(256), 0, stream>>>(z, cb, wsB, keys);
    vq_gather<<<dim3(NTOK / 64), dim3(256), 0, stream>>>(z, cb, keys, loss_acc, out);
    vq_finish<<<dim3(1), dim3(1), 0, stream>>>(loss_acc, out);
}

// Round 5
// 833.847 us; speedup vs baseline: 1.6604x; 1.6604x over previous
//
#include <hip/hip_runtime.h>
#include <math.h>

// VQ quantizer: z [65536, 256] fp32, codebook [1024, 256] fp32.
// Outputs flat: z_q [16777216] | loss [1] | indices [65536] (as float values).
//
// Numerics contract (validated R1/R4, absmax 0.0 — keep bit-identical):
//   A_t = sum(z_t^2)  -- numpy pairwise order (8-acc chains, 128-blocks, fixed tree)
//   B_n = sum(e_n^2)  -- same
//   d   = fl( fl(A+B) - 2*M ),  M = fp32 fma-accumulated dot
//   argmin: global first-min == lexicographic min of key (d_bits<<32 | idx)
//   z_q_out = fl( z + fl(e - z) ),  loss = fl(mf + fl(10*mf)), mf=(float)(Σdx²/2^24)
//
// R4 lesson: __launch_bounds__(256,4) + acc[8][8] forced VGPR=64 -> 3.4 GB scratch
// spill traffic. This version: 512 threads, acc[4][8]=32 regs, fits 128-VGPR cap.

#define NTOK     65536
#define DDIM     256
#define NCODE    1024
#define LOSS_OFF 16777216
#define IDX_OFF  16777217

// ws layout: [0] double loss_acc | [64] float wsB[1024] | [8192] u64 keys[65536]

// ---------------- kernel 0: B_n (numpy-pairwise), zero loss, init argmin keys.
__global__ void vq_prep(const float* __restrict__ cb, float* __restrict__ wsB,
                        double* __restrict__ loss_acc,
                        unsigned long long* __restrict__ keys)
{
#pragma clang fp contract(off)
    int gid = blockIdx.x * blockDim.x + threadIdx.x;
    if (gid == 0) *loss_acc = 0.0;
    unsigned long long* kp = keys + (size_t)gid * 4;
    kp[0] = kp[1] = kp[2] = kp[3] = 0xFFFFFFFFFFFFFFFFull;
    if (gid >= NCODE) return;
    const float* a = cb + gid * DDIM;
    float half[2];
    for (int h = 0; h < 2; ++h) {
        const float* b = a + h * 128;
        float r[8];
#pragma unroll
        for (int j = 0; j < 8; ++j) { float v = b[j]; r[j] = v * v; }
        for (int i = 8; i < 128; i += 8) {
#pragma unroll
            for (int j = 0; j < 8; ++j) { float v = b[i + j]; float s = v * v; r[j] = r[j] + s; }
        }
        half[h] = ((r[0] + r[1]) + (r[2] + r[3])) + ((r[4] + r[5]) + (r[6] + r[7]));
    }
    wsB[gid] = half[0] + half[1];
}

// ---------------- kernel 1: distance GEMM + per-tile argmin -> atomicMin keys.
// Grid 4096 x 512: block b -> xcd = b&7, sl = b>>3, token-tile tt = xcd*64+(sl>>3),
// code-tile ct = sl&7 (siblings of a token-tile land on one XCD's L2).
// Block tile 128 tokens x 128 codes; thread (tx,ty) = (tid&15, tid>>4) owns
// tokens 4ty..4ty+3 and codes {4tx+j, 64+4tx+j}.
__global__ __launch_bounds__(512, 4) void vq_main(const float* __restrict__ z,
                                                  const float* __restrict__ cb,
                                                  const float* __restrict__ wsB,
                                                  unsigned long long* __restrict__ keys)
{
    __shared__ float zs[32][128];   // [k][token phys]  16 KB (XOR-swizzled cols)
    __shared__ float es[32][128];   // [k][code  phys]  16 KB (XOR-swizzled cols)
    __shared__ float Bl[128];
    __shared__ float sA[128][2];

    const int tid = threadIdx.x;
    const int tx = tid & 15, ty = tid >> 4;      // ty 0..31
    const int b = blockIdx.x;
    const int xcd = b & 7, sl = b >> 3;
    const int tt = xcd * 64 + (sl >> 3);
    const int ct = sl & 7;
    const int t0 = tt * 128;
    const int n0 = ct * 128;

    if (tid < 128) Bl[tid] = wsB[n0 + tid];

    // numpy-pairwise chains for A: tid<256 -> (token = tid>>1, half = tid&1)
    float r[8];
#pragma unroll
    for (int j = 0; j < 8; ++j) r[j] = 0.0f;
    const int atok = tid >> 1, ah = tid & 1;

    float acc[4][8];
#pragma unroll
    for (int i = 0; i < 4; ++i)
#pragma unroll
        for (int j = 0; j < 8; ++j) acc[i][j] = 0.0f;

    float4 zr[2], er[2];

    // 512 threads stage a 128x32 chunk of z and of e (2 float4 each).
    // g = tid + 512*s: row = g>>3 (0..127), c4 = g&7 (float4 col within chunk).
#define STAGE_LOAD(kc_)                                                           \
    {                                                                             \
        const float* zb_ = z  + (size_t)t0 * DDIM + (kc_) * 32;                   \
        const float* eb_ = cb + (size_t)n0 * DDIM + (kc_) * 32;                   \
        _Pragma("unroll")                                                         \
        for (int s_ = 0; s_ < 2; ++s_) {                                          \
            int g_ = tid + 512 * s_; int row_ = g_ >> 3; int c4_ = g_ & 7;        \
            zr[s_] = *(const float4*)(zb_ + row_ * DDIM + c4_ * 4);               \
            er[s_] = *(const float4*)(eb_ + row_ * DDIM + c4_ * 4);               \
        }                                                                         \
    }

    STAGE_LOAD(0);

    for (int kc = 0; kc < 8; ++kc) {
        __syncthreads();
        // transpose staging writes, phys col p = row ^ ((c4&3)<<3)
        // (k = c4*4+j, so swizzle bits depend only on c4 = k>>2)
#pragma unroll
        for (int s_ = 0; s_ < 2; ++s_) {
            int g = tid + 512 * s_; int row = g >> 3; int c4 = g & 7;
            int p = row ^ ((c4 & 3) << 3);
            zs[c4 * 4 + 0][p] = zr[s_].x; zs[c4 * 4 + 1][p] = zr[s_].y;
            zs[c4 * 4 + 2][p] = zr[s_].z; zs[c4 * 4 + 3][p] = zr[s_].w;
            es[c4 * 4 + 0][p] = er[s_].x; es[c4 * 4 + 1][p] = er[s_].y;
            es[c4 * 4 + 2][p] = er[s_].z; es[c4 * 4 + 3][p] = er[s_].w;
        }
        __syncthreads();
        if (kc < 7) STAGE_LOAD(kc + 1);

        // fold numpy-pairwise ||z||^2 chains (half ah) from staged LDS
        if (tid < 256 && (kc >> 2) == ah) {
#pragma clang fp contract(off)
#pragma unroll
            for (int g = 0; g < 4; ++g)
#pragma unroll
                for (int j = 0; j < 8; ++j) {
                    int k = g * 8 + j;
                    float v = zs[k][atok ^ (((k >> 2) & 3) << 3)];
                    float s2 = v * v;
                    r[j] = r[j] + s2;
                }
        }

        // 32 k-steps: 3 x ds_read_b128 + 32 fp32 FMA per thread per step
#pragma unroll
        for (int k = 0; k < 32; ++k) {
            int cx = ((k >> 2) & 3) << 1;   // float4-granular XOR (bits 1-2 of f4 col)
            float4 a0 = *(const float4*)&zs[k][4 * (ty ^ cx)];
            float4 b0 = *(const float4*)&es[k][4 * (tx ^ cx)];
            float4 b1 = *(const float4*)&es[k][64 + 4 * (tx ^ cx)];
            float za[4] = {a0.x, a0.y, a0.z, a0.w};
            float eb[8] = {b0.x, b0.y, b0.z, b0.w, b1.x, b1.y, b1.z, b1.w};
#pragma unroll
            for (int i = 0; i < 4; ++i)
#pragma unroll
                for (int j = 0; j < 8; ++j)
                    acc[i][j] = __builtin_fmaf(za[i], eb[j], acc[i][j]);
        }
    }

    // A: numpy combine tree per half, exchange halves via LDS
    if (tid < 256) {
        float sH = ((r[0] + r[1]) + (r[2] + r[3])) + ((r[4] + r[5]) + (r[6] + r[7]));
        sA[atok][ah] = sH;
    }
    __syncthreads();
    float Aval[4];
#pragma unroll
    for (int i = 0; i < 4; ++i) {
        int tl = 4 * ty + i;
        Aval[i] = sA[tl][0] + sA[tl][1];
    }

    // d = fl(fl(A+B) - 2*M); within-tile first-min (ascending n, strict <)
    float best[4];
    int   bidx[4];
#pragma unroll
    for (int i = 0; i < 4; ++i) { best[i] = __builtin_inff(); bidx[i] = 0x7fffffff; }
#pragma unroll
    for (int i = 0; i < 4; ++i)
#pragma unroll
        for (int j = 0; j < 8; ++j) {
            int cl = (j < 4) ? (4 * tx + j) : (64 + 4 * tx + (j - 4));
            float t1 = Aval[i] + Bl[cl];
            float dist = t1 - 2.0f * acc[i][j];
            if (dist < best[i]) { best[i] = dist; bidx[i] = n0 + cl; }
        }

    // lexicographic (d, idx) min over the 16 tx-threads per token
#pragma unroll
    for (int i = 0; i < 4; ++i) {
        float d = best[i]; int w = bidx[i];
        for (int off = 8; off; off >>= 1) {
            float od = __shfl_xor(d, off);
            int   ow = __shfl_xor(w, off);
            if (od < d || (od == d && ow < w)) { d = od; w = ow; }
        }
        best[i] = d; bidx[i] = w;
    }

    // merge across code-tiles: key = d_bits<<32 | idx (d>0 so bits are monotone)
    if (tx == 0) {
#pragma unroll
        for (int i = 0; i < 4; ++i) {
            unsigned long long key =
                ((unsigned long long)__float_as_uint(best[i]) << 32) |
                (unsigned int)bidx[i];
            atomicMin(&keys[t0 + 4 * ty + i], key);
        }
    }
#undef STAGE_LOAD
}

// ---------------- kernel 2: gather z_q, indices, fp64 loss partials.
// Grid 1024 x 256: block owns 64 tokens; 16 tx-threads cooperate per token row.
__global__ __launch_bounds__(256) void vq_gather(const float* __restrict__ z,
                                                 const float* __restrict__ cb,
                                                 const unsigned long long* __restrict__ keys,
                                                 double* __restrict__ loss_acc,
                                                 float* __restrict__ out)
{
    __shared__ double lred[4];
    const int tid = threadIdx.x;
    const int tx = tid & 15, ty = tid >> 4;
    const int t0 = blockIdx.x * 64;

    double ld = 0.0;
#pragma unroll
    for (int i = 0; i < 4; ++i) {
        int t = t0 + ty * 4 + i;
        unsigned long long key = keys[t];
        int w = (int)(unsigned int)(key & 0xFFFFFFFFull);
        const float4* crow = (const float4*)(cb + (size_t)w * DDIM);
        const float4* zrow = (const float4*)(z + (size_t)t * DDIM);
        float4* orow = (float4*)(out + (size_t)t * DDIM);
#pragma unroll
        for (int q = 0; q < 4; ++q) {
            int c4 = tx * 4 + q;
            float4 e4 = crow[c4];
            float4 z4 = zrow[c4];
            float4 o;
            float dx;
            dx = e4.x - z4.x; o.x = z4.x + dx; ld += (double)(dx * dx);
            dx = e4.y - z4.y; o.y = z4.y + dx; ld += (double)(dx * dx);
            dx = e4.z - z4.z; o.z = z4.z + dx; ld += (double)(dx * dx);
            dx = e4.w - z4.w; o.w = z4.w + dx; ld += (double)(dx * dx);
            orow[c4] = o;
        }
        if (tx == 0) out[IDX_OFF + t] = (float)w;
    }

    for (int off = 32; off; off >>= 1) ld += __shfl_down(ld, off);
    int lane = tid & 63, wv = tid >> 6;
    if (lane == 0) lred[wv] = ld;
    __syncthreads();
    if (tid == 0) {
        double s = (lred[0] + lred[1]) + (lred[2] + lred[3]);
        atomicAdd(loss_acc, s);
    }
}

// ---------------- kernel 3: finalize loss = fl(mf + fl(10*mf))
__global__ void vq_finish(const double* __restrict__ loss_acc, float* __restrict__ out)
{
#pragma clang fp contract(off)
    double m = *loss_acc / 16777216.0;
    float mf = (float)m;
    float second = 10.0f * mf;
    out[LOSS_OFF] = mf + second;
}

extern "C" void kernel_launch(void* const* d_in, const int* in_sizes, int n_in,
                              void* d_out, int out_size, void* d_ws, size_t ws_size,
                              hipStream_t stream)
{
    (void)in_sizes; (void)n_in; (void)out_size; (void)ws_size;
    const float* z  = (const float*)d_in[0];
    const float* cb = (const float*)d_in[1];
    float* out = (float*)d_out;
    double* loss_acc = (double*)d_ws;                                  // 8 B
    float* wsB = (float*)((char*)d_ws + 64);                           // 4 KB
    unsigned long long* keys = (unsigned long long*)((char*)d_ws + 8192); // 512 KB

    vq_prep<<<dim3(64), dim3(256), 0, stream>>>(cb, wsB, loss_acc, keys);
    vq_main<<<dim3(4096), dim3(512), 0, stream>>>(z, cb, wsB, keys);
    vq_gather<<<dim3(NTOK / 64), dim3(256), 0, stream>>>(z, cb, keys, loss_acc, out);
    vq_finish<<<dim3(1), dim3(1), 0, stream>>>(loss_acc, out);
}

// Round 8
// 463.078 us; speedup vs baseline: 2.9899x; 1.8007x over previous
//
#include <hip/hip_runtime.h>
#include <math.h>

// VQ quantizer: z [65536, 256] fp32, codebook [1024, 256] fp32.
// Outputs flat: z_q [16777216] | loss [1] | indices [65536] (as float values).
//
// Numerics contract (validated R1/R4/R5, absmax 0.0 — keep bit-identical):
//   A_t = sum(z_t^2)  -- numpy pairwise order (8-acc chains, 128-blocks, fixed tree)
//   B_n = sum(e_n^2)  -- same
//   d   = fl( fl(A+B) - 2*M ),  M = fp32 fma-accumulated dot
//   argmin: global first-min == lexicographic min of key (d_bits<<32 | idx)
//   z_q_out = fl( z + fl(e - z) ),  loss = fl(mf + fl(10*mf)), mf=(float)(Σdx²/2^24)
//
// R4/R5 lesson: every launch_bounds with a min-occupancy arg pinned VGPR=64 and
// spilled (WRITE_SIZE GBs of scratch). This version: no min-waves demand, and
// the ||z||^2 chains move to a standalone kernel so vq_main's live state ~90 regs.

#define NTOK     65536
#define DDIM     256
#define NCODE    1024
#define LOSS_OFF 16777216
#define IDX_OFF  16777217

// ws layout: [0] double loss_acc | [64] float wsB[1024] | [8192] u64 keys[65536]
//            | [532480] float wsA[65536]

// ---------------- kernel 0: B_n (numpy-pairwise), zero loss, init argmin keys.
__global__ void vq_prep(const float* __restrict__ cb, float* __restrict__ wsB,
                        double* __restrict__ loss_acc,
                        unsigned long long* __restrict__ keys)
{
#pragma clang fp contract(off)
    int gid = blockIdx.x * blockDim.x + threadIdx.x;
    if (gid == 0) *loss_acc = 0.0;
    unsigned long long* kp = keys + (size_t)gid * 4;
    kp[0] = kp[1] = kp[2] = kp[3] = 0xFFFFFFFFFFFFFFFFull;
    if (gid >= NCODE) return;
    const float* a = cb + gid * DDIM;
    float half[2];
    for (int h = 0; h < 2; ++h) {
        const float* b = a + h * 128;
        float r[8];
#pragma unroll
        for (int j = 0; j < 8; ++j) { float v = b[j]; r[j] = v * v; }
        for (int i = 8; i < 128; i += 8) {
#pragma unroll
            for (int j = 0; j < 8; ++j) { float v = b[i + j]; float s = v * v; r[j] = r[j] + s; }
        }
        half[h] = ((r[0] + r[1]) + (r[2] + r[3])) + ((r[4] + r[5]) + (r[6] + r[7]));
    }
    wsB[gid] = half[0] + half[1];
}

// ---------------- kernel 0b: A_t (numpy-pairwise) for every token.
__global__ void vq_anorm(const float* __restrict__ z, float* __restrict__ wsA)
{
#pragma clang fp contract(off)
    int t = blockIdx.x * blockDim.x + threadIdx.x;
    const float* a = z + (size_t)t * DDIM;
    float half[2];
    for (int h = 0; h < 2; ++h) {
        const float* b = a + h * 128;
        float r[8];
#pragma unroll
        for (int j = 0; j < 8; ++j) { float v = b[j]; r[j] = v * v; }
        for (int i = 8; i < 128; i += 8) {
#pragma unroll
            for (int j = 0; j < 8; ++j) { float v = b[i + j]; float s = v * v; r[j] = r[j] + s; }
        }
        half[h] = ((r[0] + r[1]) + (r[2] + r[3])) + ((r[4] + r[5]) + (r[6] + r[7]));
    }
    wsA[t] = half[0] + half[1];
}

// ---------------- kernel 1: distance GEMM + per-tile argmin -> atomicMin keys.
// Grid 4096 x 512: block b -> xcd = b&7, sl = b>>3, token-tile tt = xcd*64+(sl>>3),
// code-tile ct = sl&7 (siblings of a token-tile land on one XCD's L2).
// Block tile 128 tokens x 128 codes; thread (tx,ty) = (tid&15, tid>>4) owns
// tokens 4ty..4ty+3 and codes {4tx+j, 64+4tx+j}.
__global__ __launch_bounds__(512) void vq_main(const float* __restrict__ z,
                                               const float* __restrict__ cb,
                                               const float* __restrict__ wsB,
                                               const float* __restrict__ wsA,
                                               unsigned long long* __restrict__ keys)
{
    __shared__ float zs[32][128];   // [k][token phys]  16 KB (XOR-swizzled cols)
    __shared__ float es[32][128];   // [k][code  phys]  16 KB (XOR-swizzled cols)
    __shared__ float Bl[128];

    const int tid = threadIdx.x;
    const int tx = tid & 15, ty = tid >> 4;      // ty 0..31
    const int b = blockIdx.x;
    const int xcd = b & 7, sl = b >> 3;
    const int tt = xcd * 64 + (sl >> 3);
    const int ct = sl & 7;
    const int t0 = tt * 128;
    const int n0 = ct * 128;

    if (tid < 128) Bl[tid] = wsB[n0 + tid];

    // per-thread token norms (bit-identical chains computed in vq_anorm)
    float4 Av4 = *(const float4*)(wsA + t0 + 4 * ty);
    float Aval[4] = {Av4.x, Av4.y, Av4.z, Av4.w};

    float acc[4][8];
#pragma unroll
    for (int i = 0; i < 4; ++i)
#pragma unroll
        for (int j = 0; j < 8; ++j) acc[i][j] = 0.0f;

    float4 zr[2], er[2];

    // 512 threads stage a 128x32 chunk of z and of e (2 float4 each).
    // g = tid + 512*s: row = g>>3 (0..127), c4 = g&7 (float4 col within chunk).
#define STAGE_LOAD(kc_)                                                           \
    {                                                                             \
        const float* zb_ = z  + (size_t)t0 * DDIM + (kc_) * 32;                   \
        const float* eb_ = cb + (size_t)n0 * DDIM + (kc_) * 32;                   \
        _Pragma("unroll")                                                         \
        for (int s_ = 0; s_ < 2; ++s_) {                                          \
            int g_ = tid + 512 * s_; int row_ = g_ >> 3; int c4_ = g_ & 7;        \
            zr[s_] = *(const float4*)(zb_ + row_ * DDIM + c4_ * 4);               \
            er[s_] = *(const float4*)(eb_ + row_ * DDIM + c4_ * 4);               \
        }                                                                         \
    }

    STAGE_LOAD(0);

    for (int kc = 0; kc < 8; ++kc) {
        __syncthreads();
        // transpose staging writes, phys col p = row ^ ((c4&3)<<3)
        // (k = c4*4+j, so swizzle bits depend only on c4 = k>>2)
#pragma unroll
        for (int s_ = 0; s_ < 2; ++s_) {
            int g = tid + 512 * s_; int row = g >> 3; int c4 = g & 7;
            int p = row ^ ((c4 & 3) << 3);
            zs[c4 * 4 + 0][p] = zr[s_].x; zs[c4 * 4 + 1][p] = zr[s_].y;
            zs[c4 * 4 + 2][p] = zr[s_].z; zs[c4 * 4 + 3][p] = zr[s_].w;
            es[c4 * 4 + 0][p] = er[s_].x; es[c4 * 4 + 1][p] = er[s_].y;
            es[c4 * 4 + 2][p] = er[s_].z; es[c4 * 4 + 3][p] = er[s_].w;
        }
        __syncthreads();
        if (kc < 7) STAGE_LOAD(kc + 1);

        // 32 k-steps: 3 x ds_read_b128 + 32 fp32 FMA per thread per step
#pragma unroll
        for (int k = 0; k < 32; ++k) {
            int cx = ((k >> 2) & 3) << 1;   // float4-granular XOR (bits 1-2 of f4 col)
            float4 a0 = *(const float4*)&zs[k][4 * (ty ^ cx)];
            float4 b0 = *(const float4*)&es[k][4 * (tx ^ cx)];
            float4 b1 = *(const float4*)&es[k][64 + 4 * (tx ^ cx)];
            float za[4] = {a0.x, a0.y, a0.z, a0.w};
            float eb[8] = {b0.x, b0.y, b0.z, b0.w, b1.x, b1.y, b1.z, b1.w};
#pragma unroll
            for (int i = 0; i < 4; ++i)
#pragma unroll
                for (int j = 0; j < 8; ++j)
                    acc[i][j] = __builtin_fmaf(za[i], eb[j], acc[i][j]);
        }
    }

    // d = fl(fl(A+B) - 2*M); within-tile first-min (ascending n, strict <)
    float best[4];
    int   bidx[4];
#pragma unroll
    for (int i = 0; i < 4; ++i) { best[i] = __builtin_inff(); bidx[i] = 0x7fffffff; }
#pragma unroll
    for (int i = 0; i < 4; ++i)
#pragma unroll
        for (int j = 0; j < 8; ++j) {
            int cl = (j < 4) ? (4 * tx + j) : (64 + 4 * tx + (j - 4));
            float t1 = Aval[i] + Bl[cl];
            float dist = t1 - 2.0f * acc[i][j];
            if (dist < best[i]) { best[i] = dist; bidx[i] = n0 + cl; }
        }

    // lexicographic (d, idx) min over the 16 tx-threads per token
#pragma unroll
    for (int i = 0; i < 4; ++i) {
        float d = best[i]; int w = bidx[i];
        for (int off = 8; off; off >>= 1) {
            float od = __shfl_xor(d, off);
            int   ow = __shfl_xor(w, off);
            if (od < d || (od == d && ow < w)) { d = od; w = ow; }
        }
        best[i] = d; bidx[i] = w;
    }

    // merge across code-tiles: key = d_bits<<32 | idx (d>0 so bits are monotone)
    if (tx == 0) {
#pragma unroll
        for (int i = 0; i < 4; ++i) {
            unsigned long long key =
                ((unsigned long long)__float_as_uint(best[i]) << 32) |
                (unsigned int)bidx[i];
            atomicMin(&keys[t0 + 4 * ty + i], key);
        }
    }
#undef STAGE_LOAD
}

// ---------------- kernel 2: gather z_q, indices, fp64 loss partials.
// Grid 1024 x 256: block owns 64 tokens; 16 tx-threads cooperate per token row.
__global__ __launch_bounds__(256) void vq_gather(const float* __restrict__ z,
                                                 const float* __restrict__ cb,
                                                 const unsigned long long* __restrict__ keys,
                                                 double* __restrict__ loss_acc,
                                                 float* __restrict__ out)
{
    __shared__ double lred[4];
    const int tid = threadIdx.x;
    const int tx = tid & 15, ty = tid >> 4;
    const int t0 = blockIdx.x * 64;

    double ld = 0.0;
#pragma unroll
    for (int i = 0; i < 4; ++i) {
        int t = t0 + ty * 4 + i;
        unsigned long long key = keys[t];
        int w = (int)(unsigned int)(key & 0xFFFFFFFFull);
        const float4* crow = (const float4*)(cb + (size_t)w * DDIM);
        const float4* zrow = (const float4*)(z + (size_t)t * DDIM);
        float4* orow = (float4*)(out + (size_t)t * DDIM);
#pragma unroll
        for (int q = 0; q < 4; ++q) {
            int c4 = tx * 4 + q;
            float4 e4 = crow[c4];
            float4 z4 = zrow[c4];
            float4 o;
            float dx;
            dx = e4.x - z4.x; o.x = z4.x + dx; ld += (double)(dx * dx);
            dx = e4.y - z4.y; o.y = z4.y + dx; ld += (double)(dx * dx);
            dx = e4.z - z4.z; o.z = z4.z + dx; ld += (double)(dx * dx);
            dx = e4.w - z4.w; o.w = z4.w + dx; ld += (double)(dx * dx);
            orow[c4] = o;
        }
        if (tx == 0) out[IDX_OFF + t] = (float)w;
    }

    for (int off = 32; off; off >>= 1) ld += __shfl_down(ld, off);
    int lane = tid & 63, wv = tid >> 6;
    if (lane == 0) lred[wv] = ld;
    __syncthreads();
    if (tid == 0) {
        double s = (lred[0] + lred[1]) + (lred[2] + lred[3]);
        atomicAdd(loss_acc, s);
    }
}

// ---------------- kernel 3: finalize loss = fl(mf + fl(10*mf))
__global__ void vq_finish(const double* __restrict__ loss_acc, float* __restrict__ out)
{
#pragma clang fp contract(off)
    double m = *loss_acc / 16777216.0;
    float mf = (float)m;
    float second = 10.0f * mf;
    out[LOSS_OFF] = mf + second;
}

extern "C" void kernel_launch(void* const* d_in, const int* in_sizes, int n_in,
                              void* d_out, int out_size, void* d_ws, size_t ws_size,
                              hipStream_t stream)
{
    (void)in_sizes; (void)n_in; (void)out_size; (void)ws_size;
    const float* z  = (const float*)d_in[0];
    const float* cb = (const float*)d_in[1];
    float* out = (float*)d_out;
    double* loss_acc = (double*)d_ws;                                      // 8 B
    float* wsB = (float*)((char*)d_ws + 64);                               // 4 KB
    unsigned long long* keys = (unsigned long long*)((char*)d_ws + 8192);  // 512 KB
    float* wsA = (float*)((char*)d_ws + 532480);                           // 256 KB

    vq_prep<<<dim3(64), dim3(256), 0, stream>>>(cb, wsB, loss_acc, keys);
    vq_anorm<<<dim3(NTOK / 256), dim3(256), 0, stream>>>(z, wsA);
    vq_main<<<dim3(4096), dim3(512), 0, stream>>>(z, cb, wsB, wsA, keys);
    vq_gather<<<dim3(NTOK / 64), dim3(256), 0, stream>>>(z, cb, keys, loss_acc, out);
    vq_finish<<<dim3(1), dim3(1), 0, stream>>>(loss_acc, out);
}